// Round 13
// baseline (334.591 us; speedup 1.0000x reference)
//
#include <hip/hip_runtime.h>

// Problem constants
#define BI    1152   // B*N = 32*36
#define NREG  36
#define DD    2048
#define RR    512
#define MBLK  144    // 4 bi, rows interleaved j*4+g
#define NBLK  256
#define ABUF  (MBLK*32)        // 4608 elems (9 KB)
#define BBUF  (NBLK*32)        // 8192 elems (16 KB)
#define BUFE  (ABUF+BBUF)      // 12800 elems = 25 KB per buffer

typedef __bf16 bf16;
typedef __bf16 bf16x8 __attribute__((ext_vector_type(8)));
typedef __bf16 bf16x4 __attribute__((ext_vector_type(4)));
typedef float  f32x4  __attribute__((ext_vector_type(4)));

__device__ __forceinline__ void gl_lds16(const void* g, void* l) {
  __builtin_amdgcn_global_load_lds(
      (const __attribute__((address_space(1))) unsigned int*)g,
      (__attribute__((address_space(3))) unsigned int*)l, 16, 0, 0);
}

// ---------------- fused prep: cvt_mm + transpose_uv + transpose_pt + uvcoord -------
__global__ void k_prep(const float* __restrict__ mm, const float* __restrict__ coords,
                       const float* __restrict__ U_feat, const float* __restrict__ V_feat,
                       const float* __restrict__ P_feat, const float* __restrict__ U_coord,
                       const float* __restrict__ V_coord, const float* __restrict__ P_coord,
                       bf16* __restrict__ mmb, bf16* __restrict__ UT, bf16* __restrict__ VT,
                       bf16* __restrict__ PTt, bf16* __restrict__ uc, bf16* __restrict__ vc) {
  __shared__ float tile[32][33];
  int bid = blockIdx.x, tid = threadIdx.x;
  if (bid < 2304) {
    int i = bid * 256 + tid;
    float4 v = ((const float4*)mm)[i];
    bf16x4 o = {(bf16)v.x, (bf16)v.y, (bf16)v.z, (bf16)v.w};
    ((bf16x4*)mmb)[i] = o;
  } else if (bid < 4352) {
    int rel = bid - 2304;
    int zz = rel >> 10, rr = rel & 1023;
    int c0 = (rr & 15) * 32, r0 = (rr >> 4) * 32;     // cols 512, rows 2048
    const float* in = zz ? V_feat : U_feat;
    bf16* outp = zz ? VT : UT;
    int tx = tid & 31, ty = tid >> 5;
#pragma unroll
    for (int k = 0; k < 4; k++)
      tile[ty + 8 * k][tx] = in[(long)(r0 + ty + 8 * k) * 512 + c0 + tx];
    __syncthreads();
#pragma unroll
    for (int k = 0; k < 4; k++)
      outp[(long)(c0 + ty + 8 * k) * 2048 + r0 + tx] = (bf16)tile[tx][ty + 8 * k];
  } else if (bid < 6400) {
    int rel = bid - 4352;
    int zz = rel >> 10, rr = rel & 1023;
    int c0 = (rr & 63) * 32, r0 = (rr >> 6) * 32;     // cols 2048, rows 512
    const float* in = zz ? P_feat : P_coord;
    int koff = zz * 512;
    int tx = tid & 31, ty = tid >> 5;
#pragma unroll
    for (int k = 0; k < 4; k++)
      tile[ty + 8 * k][tx] = in[(long)(r0 + ty + 8 * k) * 2048 + c0 + tx];
    __syncthreads();
    int kc = (koff + r0) >> 5;
#pragma unroll
    for (int k = 0; k < 4; k++) {
      int d = c0 + ty + 8 * k;
      PTt[((long)kc * 2048 + d) * 32 + tx] = (bf16)tile[tx][ty + 8 * k];
    }
  } else {
    int g = bid - 6400;
    float c0 = coords[g * 4 + 0], c1 = coords[g * 4 + 1];
    float c2 = coords[g * 4 + 2], c3 = coords[g * 4 + 3];
#pragma unroll
    for (int i = 0; i < 2; i++) {
      int r = tid + i * 256;
      uc[g * RR + r] = (bf16)(c0 * U_coord[r] + c1 * U_coord[RR + r] + c2 * U_coord[2 * RR + r] + c3 * U_coord[3 * RR + r]);
      vc[g * RR + r] = (bf16)(c0 * V_coord[r] + c1 * V_coord[RR + r] + c2 * V_coord[2 * RR + r] + c3 * V_coord[3 * RR + r]);
    }
  }
}

// ------- stage 3: uf/vf = mm @ U/V_feat, full-K, 64x128 tile, dbuf, bf16 out -------
__launch_bounds__(256)
__global__ void k_gemm_uv(const bf16* __restrict__ mmb, const bf16* __restrict__ UT,
                          const bf16* __restrict__ VT, bf16* __restrict__ uf,
                          bf16* __restrict__ vf) {
  __shared__ bf16 lds2[2][6144];   // per buf: A 64x32 (2048) + B 128x32 (4096)
  const bf16* Bmat = blockIdx.z ? VT : UT;
  bf16* outp = blockIdx.z ? vf : uf;
  int m0 = blockIdx.x * 64, n0 = blockIdx.y * 128;
  int tid = threadIdx.x, wave = tid >> 6, lane = tid & 63;
  int l15 = lane & 15, qv = lane >> 4;
  int qp_c = qv ^ ((l15 >> 1) & 3);
  int qs = (lane & 3) ^ ((lane >> 3) & 3);

  const bf16* gA = mmb + (long)(m0 + wave * 16 + (lane >> 2)) * 2048 + qs * 8;
  const bf16* gB = Bmat + (long)(n0 + wave * 32 + (lane >> 2)) * 2048 + qs * 8;
  int lA = wave * 512;
  int lB = 2048 + wave * 1024;

  auto stage = [&](int buf, int k0) {
    bf16* db = &lds2[buf][0];
    gl_lds16(gA + k0, db + lA);
    gl_lds16(gB + k0, db + lB);
    gl_lds16(gB + 16 * 2048 + k0, db + lB + 512);
  };

  f32x4 acc[4][2] = {};
  stage(0, 0);
  for (int k0 = 0; k0 < 2048; k0 += 32) {
    int cur = (k0 >> 5) & 1;
    __syncthreads();
    if (k0 + 32 < 2048) stage(cur ^ 1, k0 + 32);
    bf16x8 a[4], b[2];
#pragma unroll
    for (int mt = 0; mt < 4; mt++)
      a[mt] = *(const bf16x8*)(&lds2[cur][0] + (mt * 16 + l15) * 32 + qp_c * 8);
#pragma unroll
    for (int nt = 0; nt < 2; nt++)
      b[nt] = *(const bf16x8*)(&lds2[cur][2048] + (wave * 32 + nt * 16 + l15) * 32 + qp_c * 8);
#pragma unroll
    for (int mt = 0; mt < 4; mt++)
#pragma unroll
      for (int nt = 0; nt < 2; nt++)
        acc[mt][nt] = __builtin_amdgcn_mfma_f32_16x16x32_bf16(a[mt], b[nt], acc[mt][nt], 0, 0, 0);
  }
#pragma unroll
  for (int mt = 0; mt < 4; mt++)
#pragma unroll
    for (int nt = 0; nt < 2; nt++)
#pragma unroll
      for (int r = 0; r < 4; r++) {
        int row = m0 + mt * 16 + qv * 4 + r;
        int col = n0 + wave * 32 + nt * 16 + l15;
        outp[(long)row * RR + col] = (bf16)acc[mt][nt][r];
      }
}

// ---------------- stage 5: main fused z-build + GEMM + register max + residual ----
// R12's proven geometry (16x16x32, block 144x256, 4 waves, [row][32]+XOR swizzle,
// conflicts 0, 2 blocks/CU). A-tile is now PRODUCED IN-KERNEL: thread (wave seg s,
// lane) computes z[row = s*16+(lane>>2)][k-quad qs*8..+8] = relu(u[g]*v[j]) from
// bf16 u/v (L1/L2-resident, 5 KB unique/kstep) and writes LDS at the DMA's exact
// linear address (s*1024 + lane*16 B) -> identical layout, frag reads unchanged.
// Removes z HBM round-trip (170 MB) + the build_z kernel entirely.
__launch_bounds__(256, 2)
__global__ void k_main(const bf16* __restrict__ uc, const bf16* __restrict__ vc,
                       const bf16* __restrict__ uf, const bf16* __restrict__ vf,
                       const bf16* __restrict__ PTt, const float* __restrict__ mm,
                       float* __restrict__ out) {
  __shared__ bf16 lds[2 * BUFE];   // 50 KB
  int bid = blockIdx.x;
  int x = bid & 7, t = bid >> 3;
  int dt = t & 7, go = (t >> 3) * 8 + x;   // go 0..287 (4-bi groups)
  int d0 = dt * NBLK;
  int b = go / 9;                          // batch: go*4 / 36
  int tid = threadIdx.x, wave = tid >> 6, lane = tid & 63;
  int l15 = lane & 15, qv = lane >> 4;
  int qp_c = qv ^ ((l15 >> 1) & 3);
  int qs = (lane & 3) ^ ((lane >> 3) & 3);
  int lroff = (lane >> 2) * 32 + qs * 8;

  // A segs: waves 0-2 -> {2w, 2w+1}; wave 3 -> {6, 7, 8}
  int nseg = (wave == 3) ? 3 : 2;
  int uofs[3], vofs[3], lofsA[3];
#pragma unroll
  for (int i = 0; i < 3; i++) {
    int s = 2 * wave + i;
    if (s > 8) s = 8;
    int row = s * 16 + (lane >> 2);        // 0..143 = j*4 + g
    uofs[i] = (go * 4 + (row & 3)) * RR;
    vofs[i] = (b * 36 + (row >> 2)) * RR;
    lofsA[i] = s * 512 + lane * 8;
  }
  int kq8 = qs * 8;

  const bf16* gB = PTt + (long)d0 * 32 + wave * 2048 + lroff;
  int lB = ABUF + wave * 2048;

  auto stageB = [&](int buf, int kt) {
    bf16* db = lds + buf * BUFE;
    long kb = (long)kt * (2048L * 32);
    gl_lds16(gB + kb, db + lB);
    gl_lds16(gB + kb + 512, db + lB + 512);
    gl_lds16(gB + kb + 1024, db + lB + 1024);
    gl_lds16(gB + kb + 1536, db + lB + 1536);
  };
  // load u/v for tile kt and pack z rows into o[] (held registers; writes deferred)
  auto loadpack = [&](int kt, bf16x8* o) {
    const bf16* ub; const bf16* vb; int kk;
    if (kt < 16) { ub = uc; vb = vc; kk = kt * 32 + kq8; }
    else         { ub = uf; vb = vf; kk = (kt - 16) * 32 + kq8; }
#pragma unroll
    for (int i = 0; i < 3; i++) {
      if (i < nseg) {
        bf16x8 u8 = *(const bf16x8*)(ub + uofs[i] + kk);
        bf16x8 v8 = *(const bf16x8*)(vb + vofs[i] + kk);
#pragma unroll
        for (int e = 0; e < 8; e++)
          o[i][e] = (bf16)fmaxf((float)u8[e] * (float)v8[e], 0.f);
      }
    }
  };
  auto writez = [&](int buf, const bf16x8* o) {
    bf16* db = lds + buf * BUFE;
#pragma unroll
    for (int i = 0; i < 3; i++)
      if (i < nseg) *(bf16x8*)(db + lofsA[i]) = o[i];
  };

  f32x4 acc[9][4] = {};
  bf16x8 oz[3];
  loadpack(0, oz);
  writez(0, oz);
  stageB(0, 0);
  for (int kc = 0; kc < 32; kc++) {
    __syncthreads();
    if (kc < 31) {
      stageB((kc + 1) & 1, kc + 1);
      loadpack(kc + 1, oz);
    }
    const bf16* cur = lds + (kc & 1) * BUFE;
    bf16x8 bfr[4];
#pragma unroll
    for (int nt = 0; nt < 4; nt++)
      bfr[nt] = *(const bf16x8*)(cur + ABUF + (wave * 64 + nt * 16 + l15) * 32 + qp_c * 8);
#pragma unroll
    for (int mt = 0; mt < 9; mt++) {
      bf16x8 av = *(const bf16x8*)(cur + (mt * 16 + l15) * 32 + qp_c * 8);
#pragma unroll
      for (int nt = 0; nt < 4; nt++)
        acc[mt][nt] = __builtin_amdgcn_mfma_f32_16x16x32_bf16(av, bfr[nt], acc[mt][nt], 0, 0, 0);
    }
    if (kc < 31) writez((kc + 1) & 1, oz);
  }

  // epilogue: row-in-block = mt*16 + qv*4 + r = j*4 + g -> g = r, j = mt*4 + qv.
#pragma unroll
  for (int nt = 0; nt < 4; nt++) {
    float mx[4];
#pragma unroll
    for (int r = 0; r < 4; r++) {
      mx[r] = acc[0][nt][r];
#pragma unroll
      for (int mt = 1; mt < 9; mt++) mx[r] = fmaxf(mx[r], acc[mt][nt][r]);
      mx[r] = fmaxf(mx[r], __shfl_xor(mx[r], 16, 64));
      mx[r] = fmaxf(mx[r], __shfl_xor(mx[r], 32, 64));
    }
    if (lane < 16) {
      int col = d0 + wave * 64 + nt * 16 + lane;
#pragma unroll
      for (int r = 0; r < 4; r++) {
        long oa = (long)(go * 4 + r) * DD + col;
        out[oa] = mx[r] + mm[oa];
      }
    }
  }
}

// ---------------- launcher ----------------
extern "C" void kernel_launch(void* const* d_in, const int* in_sizes, int n_in,
                              void* d_out, int out_size, void* d_ws, size_t ws_size,
                              hipStream_t stream) {
  const float* mm     = (const float*)d_in[0];
  const float* coords = (const float*)d_in[1];
  const float* U_feat = (const float*)d_in[2];
  const float* V_feat = (const float*)d_in[3];
  const float* P_feat = (const float*)d_in[4];
  const float* U_coord= (const float*)d_in[5];
  const float* V_coord= (const float*)d_in[6];
  const float* P_coord= (const float*)d_in[7];
  float* out = (float*)d_out;

  char* ws = (char*)d_ws;
  bf16* PTt = (bf16*)(ws + 0);                 //   4,194,304 B  [kc][2048][32]
  bf16* mmb = (bf16*)(ws + 4194304);           //   4,718,592 B
  bf16* UT  = (bf16*)(ws + 8912896);           //   2,097,152 B  [512][2048]
  bf16* VT  = (bf16*)(ws + 11010048);          //   2,097,152 B
  bf16* uf  = (bf16*)(ws + 13107200);          //   1,179,648 B  [1152][512] bf16
  bf16* vf  = (bf16*)(ws + 14286848);          //   1,179,648 B
  bf16* uc  = (bf16*)(ws + 15466496);          //   1,179,648 B
  bf16* vc  = (bf16*)(ws + 16646144);          // end 17,825,792

  k_prep<<<dim3(7552), dim3(256), 0, stream>>>(mm, coords, U_feat, V_feat, P_feat,
                                               U_coord, V_coord, P_coord,
                                               mmb, UT, VT, PTt, uc, vc);
  k_gemm_uv<<<dim3(18, 4, 2), dim3(256), 0, stream>>>(mmb, UT, VT, uf, vf);
  k_main<<<dim3(2304), dim3(256), 0, stream>>>(uc, vc, uf, vf, PTt, mm, out);
}